// Round 4
// baseline (632.973 us; speedup 1.0000x reference)
//
#include <hip/hip_runtime.h>
#include <math.h>

#define GXD 128
#define GYD 128
#define GZD 128
#define VD 28
#define NRAYS 8192
#define NSAMP 128
#define NTOT (NRAYS * NSAMP)      // 1,048,576 samples
#define NBUCKET 4096              // 16x16x16 blocks of 8^3 voxels

// ws layout (bytes):
//   hist    @ 0        : 4096 u32
//   offsets @ 32768    : 4097 u32
//   cursors @ 65536    : 4096 u32
//   keys    @ 131072   : NTOT u32   (4 MB)
//   ids     @ 131072+4M: NTOT u32   (4 MB)
//   results @ 131072+8M: NTOT float4 (16 MB)

__global__ __launch_bounds__(256) void zero_hist(unsigned* __restrict__ hist) {
    const int i = blockIdx.x * 256 + threadIdx.x;
    if (i < NBUCKET) hist[i] = 0;
}

// K1: per-sample bucket key + histogram (LDS-local, flushed once per block)
__global__ __launch_bounds__(256) void hist_keys(
    const float* __restrict__ pos, unsigned* __restrict__ keys,
    unsigned* __restrict__ hist)
{
    __shared__ unsigned lh[NBUCKET];
    for (int i = threadIdx.x; i < NBUCKET; i += 256) lh[i] = 0;
    __syncthreads();
    for (int s = blockIdx.x * 256 + threadIdx.x; s < NTOT; s += gridDim.x * 256) {
        const float px = pos[3 * s + 0];
        const float py = pos[3 * s + 1];
        const float pz = pos[3 * s + 2];
        const int ix = (int)floorf(px);
        const int iy = (int)floorf(py);
        const int iz = (int)floorf(pz);
        const unsigned key = ((unsigned)(ix >> 3) << 8) |
                             ((unsigned)(iy >> 3) << 4) |
                              (unsigned)(iz >> 3);
        keys[s] = key;
        atomicAdd(&lh[key], 1u);
    }
    __syncthreads();
    for (int i = threadIdx.x; i < NBUCKET; i += 256) {
        const unsigned c = lh[i];
        if (c) atomicAdd(&hist[i], c);
    }
}

// K2: exclusive prefix sum over 4096 buckets (one 1024-thread block)
__global__ __launch_bounds__(1024) void scan_buckets(
    const unsigned* __restrict__ hist, unsigned* __restrict__ offsets,
    unsigned* __restrict__ cursors)
{
    __shared__ unsigned wsum[16];
    const int t = threadIdx.x;
    const int lane = t & 63;
    const int wv = t >> 6;
    unsigned v[4];
    unsigned s = 0;
    #pragma unroll
    for (int i = 0; i < 4; ++i) { v[i] = hist[4 * t + i]; s += v[i]; }
    unsigned sc = s;   // inclusive scan of per-thread sums within the wave
    #pragma unroll
    for (int off = 1; off < 64; off <<= 1) {
        const unsigned u = __shfl_up(sc, off, 64);
        if (lane >= off) sc += u;
    }
    if (lane == 63) wsum[wv] = sc;
    __syncthreads();
    if (t == 0) {
        unsigned acc = 0;
        for (int i = 0; i < 16; ++i) { const unsigned x = wsum[i]; wsum[i] = acc; acc += x; }
    }
    __syncthreads();
    unsigned excl = wsum[wv] + (sc - s);   // exclusive prefix of this thread's chunk
    #pragma unroll
    for (int i = 0; i < 4; ++i) {
        offsets[4 * t + i] = excl;
        cursors[4 * t + i] = excl;
        excl += v[i];
    }
    if (t == 1023) offsets[NBUCKET] = excl;   // == NTOT
}

// K3: scatter sample ids into bucket order
__global__ __launch_bounds__(256) void scatter_ids(
    const unsigned* __restrict__ keys, unsigned* __restrict__ cursors,
    unsigned* __restrict__ ids)
{
    for (int s = blockIdx.x * 256 + threadIdx.x; s < NTOT; s += gridDim.x * 256) {
        const unsigned k = keys[s];
        const unsigned idx = atomicAdd(&cursors[k], 1u);
        ids[idx] = s;
    }
}

// K4: shade. One 256-thread block per bucket; 8 lanes per sample (one per
// trilinear corner). Grid reads are clustered to a ~82 KB region per bucket.
__global__ __launch_bounds__(256) void shade(
    const float* __restrict__ grid,
    const float* __restrict__ pos,
    const unsigned* __restrict__ offsets,
    const unsigned* __restrict__ ids,
    const float* __restrict__ ang,
    float4* __restrict__ results)
{
    const unsigned b = blockIdx.x;
    const unsigned begin = offsets[b];
    const unsigned end   = offsets[b + 1];

    const int tid  = threadIdx.x;
    const int subl = tid & 7;
    const int dx   = (subl >> 2) & 1;
    const int dy   = (subl >> 1) & 1;
    const int zh   = subl & 1;

    // SH basis
    const float theta = ang[0], phi = ang[1];
    float st, ct, sp, cp;
    sincosf(theta, &st, &ct);
    sincosf(phi,   &sp, &cp);
    float basis[9];
    basis[0] = 0.28209479177387814f;
    basis[1] = 0.4886025119029199f * st * sp;
    basis[2] = 0.4886025119029199f * ct;
    basis[3] = 0.4886025119029199f * st * cp;
    basis[4] = 1.0925484305920792f * st * cp * st * sp;
    basis[5] = 1.0925484305920792f * st * sp * ct;
    basis[6] = 0.31539156525252005f * (3.0f * ct * ct - 1.0f);
    basis[7] = 1.0925484305920792f * st * cp * ct;
    basis[8] = 0.5462742152960396f * ((st * cp) * (st * cp) - (st * sp) * (st * sp));

    for (unsigned j0 = begin; j0 < end; j0 += 32) {
        const unsigned j = j0 + (unsigned)(tid >> 3);
        if (j < end) {
            const unsigned s = ids[j];
            const float px = pos[3 * s + 0];
            const float py = pos[3 * s + 1];
            const float pz = pos[3 * s + 2];
            const int ix = (int)floorf(px);
            const int iy = (int)floorf(py);
            const int iz = (int)floorf(pz);
            const float fx = px - (float)ix;
            const float fy = py - (float)iy;
            const float fz = pz - (float)iz;

            const float w = (dx ? fx : 1.0f - fx) *
                            (dy ? fy : 1.0f - fy) *
                            (zh ? fz : 1.0f - fz);

            const int base = (((ix + dx) * GYD + (iy + dy)) * GZD + (iz + zh)) * VD;
            const float4* __restrict__ q = (const float4*)(grid + base);
            float f[28];
            #pragma unroll
            for (int i = 0; i < 7; ++i)
                ((float4*)f)[i] = q[i];

            float psig = w * f[0];
            float pr = 0.0f, pg = 0.0f, pb = 0.0f;
            #pragma unroll
            for (int k = 0; k < 9; ++k) {
                pr += basis[k] * f[1 + k];
                pg += basis[k] * f[10 + k];
                pb += basis[k] * f[19 + k];
            }
            pr *= w; pg *= w; pb *= w;

            #pragma unroll
            for (int off = 1; off < 8; off <<= 1) {
                psig += __shfl_xor(psig, off, 64);
                pr   += __shfl_xor(pr,   off, 64);
                pg   += __shfl_xor(pg,   off, 64);
                pb   += __shfl_xor(pb,   off, 64);
            }
            if (subl == 0) results[s] = make_float4(psig, pr, pg, pb);
        }
    }
}

// K5: per-ray inclusive scan + weighted RGB sum. One wave per ray.
__global__ __launch_bounds__(256) void composite(
    const float4* __restrict__ results,
    const float* __restrict__ dist,
    float* __restrict__ out)
{
    const int wave = threadIdx.x >> 6;
    const int lane = threadIdx.x & 63;
    const int ray  = blockIdx.x * 4 + wave;

    const float4 a0 = results[ray * NSAMP + lane];
    const float4 a1 = results[ray * NSAMP + lane + 64];
    const float d0 = dist[ray * NSAMP + lane];
    const float d1 = dist[ray * NSAMP + lane + 64];
    const float att0 = expf(-a0.x * d0);
    const float att1 = expf(-a1.x * d1);

    float scan_lo = att0;
    #pragma unroll
    for (int off = 1; off < 64; off <<= 1) {
        const float v = __shfl_up(scan_lo, off, 64);
        if (lane >= off) scan_lo += v;
    }
    const float total_lo = __shfl(scan_lo, 63, 64);

    float scan_hi = att1;
    #pragma unroll
    for (int off = 1; off < 64; off <<= 1) {
        const float v = __shfl_up(scan_hi, off, 64);
        if (lane >= off) scan_hi += v;
    }
    const float w_lo = scan_lo * (1.0f - att0);
    const float w_hi = (total_lo + scan_hi) * (1.0f - att1);

    float o0 = w_lo * a0.y + w_hi * a1.y;
    float o1 = w_lo * a0.z + w_hi * a1.z;
    float o2 = w_lo * a0.w + w_hi * a1.w;

    #pragma unroll
    for (int off = 32; off > 0; off >>= 1) {
        o0 += __shfl_xor(o0, off, 64);
        o1 += __shfl_xor(o1, off, 64);
        o2 += __shfl_xor(o2, off, 64);
    }
    if (lane == 0) {
        out[ray * 3 + 0] = o0;
        out[ray * 3 + 1] = o1;
        out[ray * 3 + 2] = o2;
    }
}

// -------- fallback (proven R2 kernel) if ws too small --------
__global__ __launch_bounds__(1024) void plenoxel_fused32(
    const float* __restrict__ grid,
    const float* __restrict__ pos,
    const float* __restrict__ dist,
    const float* __restrict__ ang,
    float* __restrict__ out)
{
    __shared__ float4 srgb[NSAMP];
    const int ray  = blockIdx.x;
    const int tid  = threadIdx.x;
    const int s    = tid >> 3;
    const int subl = tid & 7;
    const int dx   = (subl >> 2) & 1;
    const int dy   = (subl >> 1) & 1;
    const int zh   = subl & 1;

    const float theta = ang[0], phi = ang[1];
    float st, ct, sp, cp;
    sincosf(theta, &st, &ct);
    sincosf(phi,   &sp, &cp);
    float basis[9];
    basis[0] = 0.28209479177387814f;
    basis[1] = 0.4886025119029199f * st * sp;
    basis[2] = 0.4886025119029199f * ct;
    basis[3] = 0.4886025119029199f * st * cp;
    basis[4] = 1.0925484305920792f * st * cp * st * sp;
    basis[5] = 1.0925484305920792f * st * sp * ct;
    basis[6] = 0.31539156525252005f * (3.0f * ct * ct - 1.0f);
    basis[7] = 1.0925484305920792f * st * cp * ct;
    basis[8] = 0.5462742152960396f * ((st * cp) * (st * cp) - (st * sp) * (st * sp));

    const int sidx = ray * NSAMP + s;
    const float px = pos[sidx * 3 + 0];
    const float py = pos[sidx * 3 + 1];
    const float pz = pos[sidx * 3 + 2];
    const int ix = (int)floorf(px);
    const int iy = (int)floorf(py);
    const int iz = (int)floorf(pz);
    const float fx = px - (float)ix;
    const float fy = py - (float)iy;
    const float fz = pz - (float)iz;

    const float w = (dx ? fx : 1.0f - fx) *
                    (dy ? fy : 1.0f - fy) *
                    (zh ? fz : 1.0f - fz);

    const int base = (((ix + dx) * GYD + (iy + dy)) * GZD + (iz + zh)) * VD;
    const float4* __restrict__ q = (const float4*)(grid + base);
    float f[28];
    #pragma unroll
    for (int i = 0; i < 7; ++i)
        ((float4*)f)[i] = q[i];

    float psig = w * f[0];
    float pr = 0.0f, pg = 0.0f, pb = 0.0f;
    #pragma unroll
    for (int k = 0; k < 9; ++k) {
        pr += basis[k] * f[1 + k];
        pg += basis[k] * f[10 + k];
        pb += basis[k] * f[19 + k];
    }
    pr *= w; pg *= w; pb *= w;

    #pragma unroll
    for (int off = 1; off < 8; off <<= 1) {
        psig += __shfl_xor(psig, off, 64);
        pr   += __shfl_xor(pr,   off, 64);
        pg   += __shfl_xor(pg,   off, 64);
        pb   += __shfl_xor(pb,   off, 64);
    }
    if (subl == 0) srgb[s] = make_float4(psig, pr, pg, pb);
    __syncthreads();

    if (tid < 64) {
        const int lane = tid;
        const float4 a0 = srgb[lane];
        const float4 a1 = srgb[lane + 64];
        const float d0 = dist[ray * NSAMP + lane];
        const float d1 = dist[ray * NSAMP + lane + 64];
        const float att0 = expf(-a0.x * d0);
        const float att1 = expf(-a1.x * d1);

        float scan_lo = att0;
        #pragma unroll
        for (int off = 1; off < 64; off <<= 1) {
            const float v = __shfl_up(scan_lo, off, 64);
            if (lane >= off) scan_lo += v;
        }
        const float total_lo = __shfl(scan_lo, 63, 64);
        float scan_hi = att1;
        #pragma unroll
        for (int off = 1; off < 64; off <<= 1) {
            const float v = __shfl_up(scan_hi, off, 64);
            if (lane >= off) scan_hi += v;
        }
        const float w_lo = scan_lo * (1.0f - att0);
        const float w_hi = (total_lo + scan_hi) * (1.0f - att1);

        float o0 = w_lo * a0.y + w_hi * a1.y;
        float o1 = w_lo * a0.z + w_hi * a1.z;
        float o2 = w_lo * a0.w + w_hi * a1.w;
        #pragma unroll
        for (int off = 32; off > 0; off >>= 1) {
            o0 += __shfl_xor(o0, off, 64);
            o1 += __shfl_xor(o1, off, 64);
            o2 += __shfl_xor(o2, off, 64);
        }
        if (lane == 0) {
            out[ray * 3 + 0] = o0;
            out[ray * 3 + 1] = o1;
            out[ray * 3 + 2] = o2;
        }
    }
}

extern "C" void kernel_launch(void* const* d_in, const int* in_sizes, int n_in,
                              void* d_out, int out_size, void* d_ws, size_t ws_size,
                              hipStream_t stream) {
    const float* grid = (const float*)d_in[0];
    const float* pos  = (const float*)d_in[1];
    const float* dist = (const float*)d_in[2];
    const float* ang  = (const float*)d_in[3];
    float* out = (float*)d_out;

    char* ws = (char*)d_ws;
    unsigned* hist    = (unsigned*)(ws);
    unsigned* offsets = (unsigned*)(ws + 32768);
    unsigned* cursors = (unsigned*)(ws + 65536);
    unsigned* keys    = (unsigned*)(ws + 131072);
    unsigned* ids     = (unsigned*)(ws + 131072 + (size_t)NTOT * 4);
    float4*   results = (float4*)  (ws + 131072 + (size_t)NTOT * 8);
    const size_t need = 131072 + (size_t)NTOT * (4 + 4 + 16);

    if (ws_size >= need) {
        zero_hist<<<16, 256, 0, stream>>>(hist);
        hist_keys<<<1024, 256, 0, stream>>>(pos, keys, hist);
        scan_buckets<<<1, 1024, 0, stream>>>(hist, offsets, cursors);
        scatter_ids<<<1024, 256, 0, stream>>>(keys, cursors, ids);
        shade<<<NBUCKET, 256, 0, stream>>>(grid, pos, offsets, ids, ang, results);
        composite<<<NRAYS / 4, 256, 0, stream>>>(results, dist, out);
    } else {
        plenoxel_fused32<<<NRAYS, 1024, 0, stream>>>(grid, pos, dist, ang, out);
    }
}